// Round 1
// 200.029 us; speedup vs baseline: 1.0744x; 1.0744x over previous
//
#include <hip/hip_runtime.h>

#define C_ 512
#define L_ 784
#define K_ 64
#define EPS_ 1e-12f

typedef _Float16 half_t;
typedef _Float16 half8 __attribute__((ext_vector_type(8)));
typedef _Float16 half4 __attribute__((ext_vector_type(4)));
typedef float float4v __attribute__((ext_vector_type(4)));

// ---------------------------------------------------------------------------
// kF: fused logits -> softmax -> partial agg.  grid (4, 64), block 1024
// (16 waves).  Block (bx, n) owns l-chunk [bx*192, ...) : 12 subtiles of 16 l
// (13 for bx==3; 3*192 + 208 = 784).  x is read from HBM exactly once (the
// agg A-operand re-reads the same 64-B segments through L2).
//
// Per 16-l subtile s:
//   1. issue global loads of x^T for subtile s+1 into regs (async-stage)
//   2. logits^T[l][k] via mfma 16x16x32_f16: A = xt (M=l, K=c), B = wh
//      (K=c, N=k).  16 waves = 4 k-tiles x 4 c-segments (K=512 split 4-way),
//      partials to sl[4][16 l][68].
//   3. barrier; softmax: wave wv <-> l-row, lane <-> k; shfl_xor max/sum over
//      the 64 lanes; a -> ah[k][l'] fp16, asum accumulated per-lane.
//   4. vmcnt; write staged x^T (s+1) into xt (single buffer is safe: all
//      logits reads of s finished before barrier A).
//   5. barrier; every 2nd subtile: agg^T[c][k] += via mfma: A = x from
//      GLOBAL (L2-hot, lane m = c-row, 8 l f32 -> half8), B = ah.
//      Wave = (k-tile, 8 c-tiles); acc = 8 x float4 = 32 VGPRs.
// Epilogue: transpose acc tiles through LDS -> coalesced float4 stores of
// aggP[n][bx][k][c]; asum partials reduced via LDS.
// MFMA layouts (m89/m91-verified, same as previous harness-passing kernel):
//   A: m=lane&15, kk=(lane>>4)*8+j ; B: n=lane&15, same kk ;
//   D: col(lane&15)=N, row=(lane>>4)*4+r=M.
// ---------------------------------------------------------------------------
__global__ __launch_bounds__(1024) void kF(const float* __restrict__ x,
                                           const float* __restrict__ w,
                                           float* __restrict__ aggP,
                                           float* __restrict__ asumP) {
    __shared__ half_t wh[64 * 520];   // w fp16, row stride 520 (1040 B: 16B-aligned, ~2-way banks)
    __shared__ half_t xt[16 * 520];   // x^T fp16 for one 16-l subtile
    __shared__ float  sl[4352];       // logits partials [4][16][68] / epilogue transpose buf [64][68]
    __shared__ half_t ah[64 * 40];    // a fp16 [k][32 l + pad]
    __shared__ float  asb[16 * 64];   // asum per-wave partials

    const int t    = threadIdx.x;
    const int n    = blockIdx.y;
    const int bx   = blockIdx.x;
    const int l0   = bx * 192;
    const int NT   = (bx == 3) ? 13 : 12;
    const int wv   = t >> 6;
    const int lane = t & 63;
    const int n16  = lane & 15;
    const int q    = lane >> 4;

    const float* xn = x + (size_t)n * (C_ * L_);

    // ---- stage w -> wh (once per block; previous kA restaged it 8x) ----
#pragma unroll
    for (int i = 0; i < 8; ++i) {
        int e  = t + 1024 * i;        // 0..8191
        int k  = e >> 7;              // 128 float4 per k row
        int cq = e & 127;
        float4v f = *(const float4v*)(w + (size_t)k * C_ + 4 * cq);
        *(half4*)&wh[k * 520 + 4 * cq] =
            half4{(half_t)f.x, (half_t)f.y, (half_t)f.z, (half_t)f.w};
    }

    // ---- stage x^T subtile 0: thread (l = t&15, cg = t>>4 -> 8 c rows) ----
    {
        const int l  = t & 15;
        const int cg = t >> 4;
        const float* src = xn + l0 + l;
        float v0[8];
#pragma unroll
        for (int j = 0; j < 8; ++j) v0[j] = src[(size_t)(8 * cg + j) * L_];
        half8 h;
#pragma unroll
        for (int j = 0; j < 8; ++j) h[j] = (half_t)v0[j];
        *(half8*)&xt[l * 520 + 8 * cg] = h;
    }

    float4v agc[8];
#pragma unroll
    for (int i = 0; i < 8; ++i) agc[i] = float4v{0.f, 0.f, 0.f, 0.f};
    float asum_reg = 0.f;

    const int kt  = wv & 3;    // logits k-tile
    const int cs  = wv >> 2;   // logits c-segment (K=512 split 4-way)
    const int kt2 = wv & 3;    // agg k-tile
    const int cg2 = wv >> 2;   // agg c-group (8 c-tiles each)

    __syncthreads();

    float pre[8];
    for (int s = 0; s < NT; ++s) {
        // 1. async-stage: issue x^T loads for s+1 (consumed at step 4)
        if (s + 1 < NT) {
            const float* src = xn + l0 + (s + 1) * 16 + (t & 15);
            const int cg = t >> 4;
#pragma unroll
            for (int j = 0; j < 8; ++j) pre[j] = src[(size_t)(8 * cg + j) * L_];
        }
        // 2. logits^T for subtile s
        {
            float4v lac = {0.f, 0.f, 0.f, 0.f};
#pragma unroll
            for (int st = 0; st < 4; ++st) {
                const int c0 = cs * 128 + st * 32;
                half8 A = *(const half8*)&xt[n16 * 520 + c0 + 8 * q];
                half8 B = *(const half8*)&wh[(kt * 16 + n16) * 520 + c0 + 8 * q];
                lac = __builtin_amdgcn_mfma_f32_16x16x32_f16(A, B, lac, 0, 0, 0);
            }
#pragma unroll
            for (int r = 0; r < 4; ++r)
                sl[cs * 1088 + (4 * q + r) * 68 + kt * 16 + n16] = lac[r];
        }
        __syncthreads();   // barrier A
        // 3. softmax: wave wv = l-row, lane = k (all 1024 threads active)
        {
            float lg = sl[wv * 68 + lane] + sl[1088 + wv * 68 + lane] +
                       sl[2176 + wv * 68 + lane] + sl[3264 + wv * 68 + lane];
            float mx = lg;
#pragma unroll
            for (int off = 32; off; off >>= 1) mx = fmaxf(mx, __shfl_xor(mx, off, 64));
            float e  = __expf(lg - mx);
            float sm = e;
#pragma unroll
            for (int off = 32; off; off >>= 1) sm += __shfl_xor(sm, off, 64);
            float a = e / sm;
            asum_reg += a;
            ah[lane * 40 + (s & 1) * 16 + wv] = (half_t)a;
        }
        // 4. write staged x^T for s+1 (xt reads for s all completed pre-A)
        if (s + 1 < NT) {
            half8 h;
#pragma unroll
            for (int j = 0; j < 8; ++j) h[j] = (half_t)pre[j];
            *(half8*)&xt[(t & 15) * 520 + 8 * (t >> 4)] = h;
        }
        __syncthreads();   // barrier B
        // 5. agg phase at each pair boundary (K=32 over l)
        const bool tail_single = (s == NT - 1) && ((s & 1) == 0);
        if (tail_single) {   // odd NT: zero ah[:,16:32] so K=32 MFMA is safe
            ah[(t >> 4) * 40 + 16 + (t & 15)] = (half_t)0.f;
            __syncthreads();
        }
        if ((s & 1) || tail_single) {
            const int l0p = l0 + (s & ~1) * 16;
#pragma unroll
            for (int i = 0; i < 8; ++i) {
                const int c = (cg2 * 8 + i) * 16 + n16;
                int bl = l0p + 8 * q;
                if (bl > 776) bl = 776;   // clamp OOB tail reads (ah==0 there)
                const float* xp = xn + (size_t)c * L_ + bl;
                float4v f0 = *(const float4v*)xp;
                float4v f1 = *(const float4v*)(xp + 4);
                half8 A = {(half_t)f0.x, (half_t)f0.y, (half_t)f0.z, (half_t)f0.w,
                           (half_t)f1.x, (half_t)f1.y, (half_t)f1.z, (half_t)f1.w};
                half8 B = *(const half8*)&ah[(kt2 * 16 + n16) * 40 + 8 * q];
                agc[i] = __builtin_amdgcn_mfma_f32_16x16x32_f16(A, B, agc[i], 0, 0, 0);
            }
        }
    }

    // ---- epilogue: asum partials + agg transpose-store ----
    asb[wv * 64 + lane] = asum_reg;

#pragma unroll
    for (int i = 0; i < 8; ++i) {   // fully unrolled: agc[i] stays in regs
        __syncthreads();
        // dump tile i: 16 disjoint 16x16 blocks into sl[64][68]
#pragma unroll
        for (int r = 0; r < 4; ++r)
            sl[(kt2 * 16 + n16) * 68 + cg2 * 16 + 4 * q + r] = agc[i][r];
        __syncthreads();
        // coalesced store: thread -> (k = t>>4, g = (t>>2)&3, e2 = t&3)
        const int k  = t >> 4;
        const int g  = (t >> 2) & 3;
        const int e2 = t & 3;
        float4v f = *(const float4v*)&sl[k * 68 + g * 16 + 4 * e2];
        *(float4v*)(aggP + (((size_t)n * 4 + bx) * 64 + k) * C_ +
                    g * 128 + i * 16 + 4 * e2) = f;
    }
    __syncthreads();
    if (t < 64) {
        float s_ = 0.f;
        for (int j = 0; j < 16; ++j) s_ += asb[j * 64 + t];
        asumP[((size_t)n * 4 + bx) * 64 + t] = s_;
    }
}

// ---------------------------------------------------------------------------
// kC: reduce 4 agg partials, vlad = agg - asum*cent, intra-normalize per
// (n,k) over C; global norm is exactly 8 (64 unit rows).  grid (8,64), 256.
// ---------------------------------------------------------------------------
__global__ __launch_bounds__(256) void kC(const float* __restrict__ aggP,
                                          const float* __restrict__ cent,
                                          const float* __restrict__ asumP,
                                          float* __restrict__ out) {
    __shared__ float asumS[8];
    const int t  = threadIdx.x;
    const int n  = blockIdx.y;
    const int k0 = blockIdx.x * 8;
    if (t < 8) {
        float s = 0.f;
        for (int j = 0; j < 4; ++j) s += asumP[((size_t)n * 4 + j) * 64 + k0 + t];
        asumS[t] = s;
    }
    __syncthreads();
    const int wv   = t >> 6;
    const int lane = t & 63;
    for (int r = wv; r < 8; r += 4) {
        const int k = k0 + r;
        const float as = asumS[r];
        const float* a0 = aggP + (((size_t)n * 4 + 0) * 64 + k) * C_;
        const float* a1 = aggP + (((size_t)n * 4 + 1) * 64 + k) * C_;
        const float* a2 = aggP + (((size_t)n * 4 + 2) * 64 + k) * C_;
        const float* a3 = aggP + (((size_t)n * 4 + 3) * 64 + k) * C_;
        const float* cp = cent + (size_t)k * C_;
        float v[8];
        float ss = 0.f;
#pragma unroll
        for (int j = 0; j < 8; ++j) {
            const int c = lane + 64 * j;
            float val = a0[c] + a1[c] + a2[c] + a3[c] - as * cp[c];
            v[j] = val;
            ss += val * val;
        }
#pragma unroll
        for (int off = 32; off; off >>= 1) ss += __shfl_xor(ss, off, 64);
        const float scale = 1.f / (fmaxf(sqrtf(ss), EPS_) * 8.f);
        float* op = out + (size_t)n * (K_ * C_) + (size_t)k * C_;
#pragma unroll
        for (int j = 0; j < 8; ++j) op[lane + 64 * j] = v[j] * scale;
    }
}

extern "C" void kernel_launch(void* const* d_in, const int* in_sizes, int n_in,
                              void* d_out, int out_size, void* d_ws, size_t ws_size,
                              hipStream_t stream) {
    (void)in_sizes; (void)n_in; (void)out_size; (void)ws_size;
    const float* x    = (const float*)d_in[0];   // (64, 512, 28, 28) fp32
    const float* w    = (const float*)d_in[1];   // (64, 512) fp32
    const float* cent = (const float*)d_in[2];   // (64, 512) fp32
    float* out = (float*)d_out;                  // (64, 32768) fp32

    // ws: aggP f32 [64 n][4 bx][64 k][512 c] = 32 MB ; asumP f32 [64][4][64]
    // = 64 KB.  Total 32.1 MB (ws_size >= 46 MB known-good from prior rounds).
    char* base = (char*)d_ws;
    float* aggP  = (float*)base;
    float* asumP = aggP + (size_t)64 * 4 * 64 * 512;

    kF<<<dim3(4, 64), 1024, 0, stream>>>(x, w, aggP, asumP);
    kC<<<dim3(8, 64), 256, 0, stream>>>(aggP, cent, asumP, out);
}

// Round 2
// 183.252 us; speedup vs baseline: 1.1728x; 1.0916x over previous
//
#include <hip/hip_runtime.h>

#define C_ 512
#define L_ 784
#define K_ 64
#define EPS_ 1e-12f

typedef _Float16 half_t;
typedef _Float16 half8 __attribute__((ext_vector_type(8)));
typedef float float4v __attribute__((ext_vector_type(4)));

// ---------------------------------------------------------------------------
// kF v2: fused logits -> softmax -> partial agg.  grid (4, 64), block 1024
// (16 waves).  x is read from HBM exactly ONCE and consumed twice from LDS:
//   xt [16 l][520 c]  (c-contig rows)  -> logits A-operand
//   xc [2 buf][512 c][40 l] (l-contig) -> agg B-operand (double-buffered pair)
// w lives in REGISTERS (wf[4], 16 VGPR): wave (kt,cs) owns w[16k][128c].
// Per 16-l subtile s:
//   1. issue 2x dwordx4 prefetch of x for s+1 (thread = (c, l-octet))
//   2. logits^T: D[l][k] = mfma(A=xt, B=wf), partials sl[cs][16 l][65]
//   3. barrier A; softmax: wave=l-row, lane=k, shfl_xor over 64 lanes;
//      a -> ah[k][32 l] fp16; asum_reg accumulated
//   4. cvt staged regs -> write xt (s+1) + xc[buf(s+1)]
//   5. barrier B; every 2nd subtile: agg D[k][c] += mfma(A=ah, B=xc) --
//      pure LDS, no global loads.
// Epilogue: direct coalesced stores of aggP (D already [k][c]); asum via sl.
// MFMA maps (m89/m91, same as harness-passing r0 kernel):
//   A: m=lane&15, kk=(lane>>4)*8+j ; B: n=lane&15, same kk ;
//   D: row=(lane>>4)*4+r (M), col=lane&15 (N).
// ---------------------------------------------------------------------------
__global__ __launch_bounds__(1024) void kF(const float* __restrict__ x,
                                           const float* __restrict__ w,
                                           float* __restrict__ aggP,
                                           float* __restrict__ asumP) {
    __shared__ half_t xt[16 * 520];      // 16.6 KB  x^T current subtile
    __shared__ half_t xc[2][512 * 40];   // 80.0 KB  x c-major, l-pair dbuf
    __shared__ float  sl[4 * 16 * 65];   // 16.6 KB  logits partials / asum buf
    __shared__ half_t ah[64 * 40];       //  5.1 KB  a [k][32 l]

    const int t    = threadIdx.x;
    const int n    = blockIdx.y;
    const int bx   = blockIdx.x;
    const int l0   = bx * 192;
    const int NT   = (bx == 3) ? 13 : 12;
    const int wv   = t >> 6;
    const int lane = t & 63;
    const int m16  = lane & 15;
    const int q    = lane >> 4;
    const int kt   = wv & 3;   // k-tile (logits and agg)
    const int cs   = wv >> 2;  // c-segment (logits) / c-group (agg)

    const float* xn = x + (size_t)n * (C_ * L_);

    // ---- w -> registers: wave (kt,cs) B-fragments for 4 K=32 substeps ----
    half8 wf[4];
    {
        const float* wr = w + (size_t)(kt * 16 + m16) * C_ + cs * 128 + 8 * q;
#pragma unroll
        for (int st = 0; st < 4; ++st) {
            float4v f0 = *(const float4v*)(wr + 32 * st);
            float4v f1 = *(const float4v*)(wr + 32 * st + 4);
            wf[st] = half8{(half_t)f0.x, (half_t)f0.y, (half_t)f0.z, (half_t)f0.w,
                           (half_t)f1.x, (half_t)f1.y, (half_t)f1.z, (half_t)f1.w};
        }
    }

    // ---- staging geometry: thread = (c row, l-octet); 32 B contiguous ----
    const int sc  = t >> 1;
    const int slq = t & 1;
    const float* xs = xn + (size_t)sc * L_ + l0 + 8 * slq;

    // stage subtile 0
    {
        float4v f0 = *(const float4v*)xs;
        float4v f1 = *(const float4v*)(xs + 4);
        half8 h = {(half_t)f0.x, (half_t)f0.y, (half_t)f0.z, (half_t)f0.w,
                   (half_t)f1.x, (half_t)f1.y, (half_t)f1.z, (half_t)f1.w};
        *(half8*)&xc[0][sc * 40 + 8 * slq] = h;
#pragma unroll
        for (int j = 0; j < 8; ++j) xt[(8 * slq + j) * 520 + sc] = h[j];
    }

    float4v agc[8];
#pragma unroll
    for (int i = 0; i < 8; ++i) agc[i] = float4v{0.f, 0.f, 0.f, 0.f};
    float asum_reg = 0.f;

    __syncthreads();

    for (int s = 0; s < NT; ++s) {
        // 1. prefetch x for subtile s+1 (consumed at step 4)
        float4v p0, p1;
        const bool pf = (s + 1 < NT);
        if (pf) {
            const float* p = xs + (s + 1) * 16;
            p0 = *(const float4v*)p;
            p1 = *(const float4v*)(p + 4);
        }
        // 2. logits^T for subtile s: D[l][k]
        {
            float4v lac = {0.f, 0.f, 0.f, 0.f};
#pragma unroll
            for (int st = 0; st < 4; ++st) {
                half8 A = *(const half8*)&xt[m16 * 520 + cs * 128 + st * 32 + 8 * q];
                lac = __builtin_amdgcn_mfma_f32_16x16x32_f16(A, wf[st], lac, 0, 0, 0);
            }
#pragma unroll
            for (int r = 0; r < 4; ++r)
                sl[cs * 1040 + (4 * q + r) * 65 + kt * 16 + m16] = lac[r];
        }
        __syncthreads();   // barrier A
        // 3. softmax: wave wv = l-row, lane = k (all 1024 threads active)
        {
            float lg = sl[wv * 65 + lane] + sl[1040 + wv * 65 + lane] +
                       sl[2080 + wv * 65 + lane] + sl[3120 + wv * 65 + lane];
            float mx = lg;
#pragma unroll
            for (int off = 32; off; off >>= 1) mx = fmaxf(mx, __shfl_xor(mx, off, 64));
            float e = __expf(lg - mx);
            float sm = e;
#pragma unroll
            for (int off = 32; off; off >>= 1) sm += __shfl_xor(sm, off, 64);
            float a = e / sm;
            asum_reg += a;
            ah[lane * 40 + (s & 1) * 16 + wv] = (half_t)a;
        }
        // 4. write staged x (s+1): xt reads of s all completed before A
        if (pf) {
            half8 h = {(half_t)p0.x, (half_t)p0.y, (half_t)p0.z, (half_t)p0.w,
                       (half_t)p1.x, (half_t)p1.y, (half_t)p1.z, (half_t)p1.w};
            const int sp = s + 1;
            *(half8*)&xc[(sp >> 1) & 1][sc * 40 + (sp & 1) * 16 + 8 * slq] = h;
#pragma unroll
            for (int j = 0; j < 8; ++j) xt[(8 * slq + j) * 520 + sc] = h[j];
        }
        __syncthreads();   // barrier B
        // 5. agg every pair boundary: D[k][c] from pure LDS
        const bool tail_single = (s == NT - 1) && !(s & 1);
        if (tail_single) {   // odd NT: zero ah[:,16:32] so K=32 MFMA is safe
            ah[(t >> 4) * 40 + 16 + (t & 15)] = (half_t)0.f;
            __syncthreads();
        }
        if ((s & 1) || tail_single) {
            const half_t* xcb = xc[(s >> 1) & 1];
            half8 A = *(const half8*)&ah[(kt * 16 + m16) * 40 + 8 * q];
#pragma unroll
            for (int i = 0; i < 8; ++i) {
                half8 B = *(const half8*)&xcb[((cs * 8 + i) * 16 + m16) * 40 + 8 * q];
                agc[i] = __builtin_amdgcn_mfma_f32_16x16x32_f16(A, B, agc[i], 0, 0, 0);
            }
        }
    }

    // ---- epilogue: asum reduce (sl reused) + direct coalesced agg stores ----
    sl[wv * 64 + lane] = asum_reg;
    __syncthreads();
    if (t < 64) {
        float s_ = 0.f;
#pragma unroll
        for (int j = 0; j < 16; ++j) s_ += sl[j * 64 + t];
        asumP[((size_t)n * 4 + bx) * 64 + t] = s_;
    }
    float* ap = aggP + (((size_t)n * 4 + bx) * 64) * (size_t)C_;
#pragma unroll
    for (int i = 0; i < 8; ++i)
#pragma unroll
        for (int r = 0; r < 4; ++r)
            ap[(size_t)(kt * 16 + 4 * q + r) * C_ + (cs * 8 + i) * 16 + m16] = agc[i][r];
}

// ---------------------------------------------------------------------------
// kC: reduce 4 agg partials, vlad = agg - asum*cent, intra-normalize per
// (n,k) over C; global norm is exactly 8 (64 unit rows).  grid (8,64), 256.
// ---------------------------------------------------------------------------
__global__ __launch_bounds__(256) void kC(const float* __restrict__ aggP,
                                          const float* __restrict__ cent,
                                          const float* __restrict__ asumP,
                                          float* __restrict__ out) {
    __shared__ float asumS[8];
    const int t  = threadIdx.x;
    const int n  = blockIdx.y;
    const int k0 = blockIdx.x * 8;
    if (t < 8) {
        float s = 0.f;
        for (int j = 0; j < 4; ++j) s += asumP[((size_t)n * 4 + j) * 64 + k0 + t];
        asumS[t] = s;
    }
    __syncthreads();
    const int wv   = t >> 6;
    const int lane = t & 63;
    for (int r = wv; r < 8; r += 4) {
        const int k = k0 + r;
        const float as = asumS[r];
        const float* a0 = aggP + (((size_t)n * 4 + 0) * 64 + k) * C_;
        const float* a1 = aggP + (((size_t)n * 4 + 1) * 64 + k) * C_;
        const float* a2 = aggP + (((size_t)n * 4 + 2) * 64 + k) * C_;
        const float* a3 = aggP + (((size_t)n * 4 + 3) * 64 + k) * C_;
        const float* cp = cent + (size_t)k * C_;
        float v[8];
        float ss = 0.f;
#pragma unroll
        for (int j = 0; j < 8; ++j) {
            const int c = lane + 64 * j;
            float val = a0[c] + a1[c] + a2[c] + a3[c] - as * cp[c];
            v[j] = val;
            ss += val * val;
        }
#pragma unroll
        for (int off = 32; off; off >>= 1) ss += __shfl_xor(ss, off, 64);
        const float scale = 1.f / (fmaxf(sqrtf(ss), EPS_) * 8.f);
        float* op = out + (size_t)n * (K_ * C_) + (size_t)k * C_;
#pragma unroll
        for (int j = 0; j < 8; ++j) op[lane + 64 * j] = v[j] * scale;
    }
}

extern "C" void kernel_launch(void* const* d_in, const int* in_sizes, int n_in,
                              void* d_out, int out_size, void* d_ws, size_t ws_size,
                              hipStream_t stream) {
    (void)in_sizes; (void)n_in; (void)out_size; (void)ws_size;
    const float* x    = (const float*)d_in[0];   // (64, 512, 28, 28) fp32
    const float* w    = (const float*)d_in[1];   // (64, 512) fp32
    const float* cent = (const float*)d_in[2];   // (64, 512) fp32
    float* out = (float*)d_out;                  // (64, 32768) fp32

    // ws: aggP f32 [64 n][4 bx][64 k][512 c] = 33.6 MB ; asumP f32 [64][4][64]
    // = 64 KB.  Total 33.7 MB (ws_size >= 46 MB known-good).
    char* base = (char*)d_ws;
    float* aggP  = (float*)base;
    float* asumP = aggP + (size_t)64 * 4 * 64 * 512;

    kF<<<dim3(4, 64), 1024, 0, stream>>>(x, w, aggP, asumP);
    kC<<<dim3(8, 64), 256, 0, stream>>>(aggP, cent, asumP, out);
}